// Round 2
// baseline (3339.809 us; speedup 1.0000x reference)
//
#include <hip/hip_runtime.h>
#include <stdint.h>

// Problem constants
#define N4   4096
#define H0   256
#define SIDE 1024
#define DIN  512
#define HCAT 768      // H0 + DIN
#define H1   128
#define NC   5
#define NUV  16777216ULL   // 4096*4096

// ---------------------------------------------------------------- k_counts
__global__ __launch_bounds__(256) void k_counts(const int* __restrict__ u,
                                                const int* __restrict__ v,
                                                int* __restrict__ cu,
                                                int* __restrict__ cv) {
    int i = blockIdx.x * 256 + threadIdx.x;   // 4096 threads
    atomicAdd(&cu[u[i]], 1);
    atomicAdd(&cv[v[i]], 1);
}

// ---------------------------------------------------------------- k_code
// code[p][q] = c+1 where adj[c][p][q] != 0 (at most one c), else 0
__global__ __launch_bounds__(256) void k_code(const float* __restrict__ adj,
                                              uchar4* __restrict__ code4) {
    size_t g = (size_t)blockIdx.x * 256 + threadIdx.x;   // unit of 4 elems
    size_t base = g * 4;
    uchar4 out = {0, 0, 0, 0};
    #pragma unroll
    for (int c = 0; c < NC; c++) {
        float4 s = *(const float4*)(adj + (size_t)c * NUV + base);
        out.x = (s.x != 0.f) ? (unsigned char)(c + 1) : out.x;
        out.y = (s.y != 0.f) ? (unsigned char)(c + 1) : out.y;
        out.z = (s.z != 0.f) ? (unsigned char)(c + 1) : out.z;
        out.w = (s.w != 0.f) ? (unsigned char)(c + 1) : out.w;
    }
    code4[g] = out;
}

// ---------------------------------------------------------------- k_transpose (byte, 64x64 tiles)
__global__ __launch_bounds__(256) void k_transpose(const uint8_t* __restrict__ src,
                                                   uint8_t* __restrict__ dst) {
    __shared__ __align__(16) uint8_t tile[64][80];
    int t = threadIdx.x;
    int row = t >> 2;            // 0..63
    int seg = (t & 3) * 16;      // 0,16,32,48
    int p0 = blockIdx.y * 64, q0 = blockIdx.x * 64;
    uint4 vdat = *(const uint4*)(src + (size_t)(p0 + row) * N4 + q0 + seg);
    *(uint4*)(&tile[row][seg]) = vdat;
    __syncthreads();
    union { uint4 u4; uint8_t b[16]; } o;
    #pragma unroll
    for (int l = 0; l < 16; l++) o.b[l] = tile[seg + l][row];
    *(uint4*)(dst + (size_t)(q0 + row) * N4 + p0 + seg) = o.u4;
}

// ---------------------------------------------------------------- k_wcumsum
// out[r][node][h] = cnt[node] * cumsum_r(w)[r][node][h]
__global__ __launch_bounds__(256) void k_wcumsum(const float* __restrict__ w,
                                                 const int* __restrict__ cnt,
                                                 float* __restrict__ out) {
    int node = blockIdx.x, h = threadIdx.x;
    float c = (float)cnt[node];
    float acc = 0.f;
    #pragma unroll
    for (int r = 0; r < NC; r++) {
        size_t idx = ((size_t)r * N4 + node) * H0 + h;
        acc += w[idx];
        out[idx] = acc * c;
    }
}

// ---------------------------------------------------------------- k_gather
// outNN[p][h] = sum_q [code>0] * Wsrc[code-1][q][h];  outDeg[p] = sum_q [code>0]*cntOther[q]
__global__ __launch_bounds__(256) void k_gather(const uint8_t* __restrict__ codeRows,
                                                const float* __restrict__ Wsrc,
                                                const int* __restrict__ cntOther,
                                                float* __restrict__ outNN,
                                                float* __restrict__ outDeg) {
    __shared__ __align__(16) uint8_t crow[4096];
    __shared__ float cw[4096];
    int p = blockIdx.x, h = threadIdx.x;
    // stage code row (4096 B) and other-side counts (as float)
    reinterpret_cast<uint4*>(crow)[h] = reinterpret_cast<const uint4*>(codeRows + (size_t)p * N4)[h];
    const int4* co4 = reinterpret_cast<const int4*>(cntOther);
    #pragma unroll
    for (int l = 0; l < 4; l++) {
        int4 ci = co4[h + l * 256];
        reinterpret_cast<float4*>(cw)[h + l * 256] =
            make_float4((float)ci.x, (float)ci.y, (float)ci.z, (float)ci.w);
    }
    __syncthreads();
    float acc = 0.f, deg = 0.f;
    for (int q = 0; q < 4096; q++) {
        int r = crow[q];
        if (r) {   // wave-uniform branch (crow[q] identical across lanes)
            acc += Wsrc[((size_t)(r - 1) * N4 + q) * H0 + h];
            deg += cw[q];
        }
    }
    outNN[(size_t)p * H0 + h] = acc;
    if (h == 0) outDeg[p] = deg;
}

// ---------------------------------------------------------------- k_z
// cat[i][h] = relu(nn[idxs[i]][h] / deg[idxo[i]])  (0 when deg==0)
__global__ __launch_bounds__(256) void k_z(const float* __restrict__ nn,
                                           const int* __restrict__ idxs,
                                           const int* __restrict__ idxo,
                                           const float* __restrict__ deg,
                                           float* __restrict__ cat) {
    int i = blockIdx.x, h = threadIdx.x;
    float d = deg[idxo[i]];
    float inv = d > 0.f ? 1.f / d : 0.f;
    float val = nn[(size_t)idxs[i] * H0 + h] * inv;
    cat[(size_t)i * HCAT + h] = fmaxf(val, 0.f);
}

// ---------------------------------------------------------------- generic NT GEMM (fp32)
// C[i,n] = act( sum_k A[row(i),k]*B[n,k] (+bias[n]) ), A/B row-major K-contiguous
template <int TM, int TN, int BK, int RM, int RN, bool GATHER, bool BIAS, bool RELU>
__global__ __launch_bounds__(256) void k_gemm(const float* __restrict__ A, int lda,
                                              const int* __restrict__ rowmap,
                                              const float* __restrict__ B, int ldb,
                                              const float* __restrict__ bias,
                                              float* __restrict__ C, int ldc, int K,
                                              size_t bzs, size_t czs) {
    constexpr int TX = TN / RN;
    constexpr int TY = TM / RM;
    static_assert(TX * TY == 256, "block must be 256");
    __shared__ float As[BK][TM + 4];
    __shared__ float Bs[BK][TN + 4];
    int tid = threadIdx.x;
    int tx = tid % TX, ty = tid / TX;
    int i0 = blockIdx.x * TM, n0 = blockIdx.y * TN;
    const float* Bz = B + (size_t)blockIdx.z * bzs;
    float acc[RM][RN] = {};
    for (int k0 = 0; k0 < K; k0 += BK) {
        for (int g = tid; g < TM * BK / 4; g += 256) {
            int i = g / (BK / 4), kc = g % (BK / 4);
            int row = GATHER ? rowmap[i0 + i] : (i0 + i);
            float4 val = *(const float4*)(A + (size_t)row * lda + k0 + kc * 4);
            As[kc * 4 + 0][i] = val.x; As[kc * 4 + 1][i] = val.y;
            As[kc * 4 + 2][i] = val.z; As[kc * 4 + 3][i] = val.w;
        }
        for (int g = tid; g < TN * BK / 4; g += 256) {
            int n = g / (BK / 4), kc = g % (BK / 4);
            float4 val = *(const float4*)(Bz + (size_t)(n0 + n) * ldb + k0 + kc * 4);
            Bs[kc * 4 + 0][n] = val.x; Bs[kc * 4 + 1][n] = val.y;
            Bs[kc * 4 + 2][n] = val.z; Bs[kc * 4 + 3][n] = val.w;
        }
        __syncthreads();
        #pragma unroll
        for (int k = 0; k < BK; k++) {
            float av[RM], bv[RN];
            #pragma unroll
            for (int m = 0; m < RM; m++) av[m] = As[k][ty * RM + m];
            #pragma unroll
            for (int n = 0; n < RN; n++) bv[n] = Bs[k][tx * RN + n];
            #pragma unroll
            for (int m = 0; m < RM; m++)
                #pragma unroll
                for (int n = 0; n < RN; n++)
                    acc[m][n] = fmaf(av[m], bv[n], acc[m][n]);
        }
        __syncthreads();
    }
    float* Cz = C + (size_t)blockIdx.z * czs;
    #pragma unroll
    for (int m = 0; m < RM; m++) {
        int ig = i0 + ty * RM + m;
        #pragma unroll
        for (int n = 0; n < RN; n++) {
            float vv = acc[m][n];
            if (BIAS) vv += bias[n0 + tx * RN + n];
            if (RELU) vv = fmaxf(vv, 0.f);
            Cz[(size_t)ig * ldc + n0 + tx * RN + n] = vv;
        }
    }
}

// ---------------------------------------------------------------- k_Pt : Pt[b][e][d] = P[b][d][e]
__global__ __launch_bounds__(256) void k_Pt(const float* __restrict__ P, float* __restrict__ Pt) {
    int tid = blockIdx.x * 256 + threadIdx.x;   // 32768
    int b = tid >> 14;
    int d = (tid >> 7) & 127;
    int e = tid & 127;
    Pt[((size_t)b * 128 + e) * 128 + d] = P[tid];
}

// ---------------------------------------------------------------- k_scores (fused decoder+softmax+reductions)
__global__ __launch_bounds__(256) void k_scores(const float* __restrict__ t01,   // [2][4096][128]
                                                const float* __restrict__ vh,    // [4096][128]
                                                const uint8_t* __restrict__ code,
                                                const int* __restrict__ uidx,
                                                const int* __restrict__ vidx,
                                                const float* __restrict__ a_f,   // [2][5]
                                                float* __restrict__ mhat,        // [4096][4096]
                                                float* __restrict__ accum) {     // loss, se, nobs
    __shared__ float T0s[64][68], T1s[64][68], Vs[64][68];
    __shared__ int su[64], sv[64];
    __shared__ float sa[16];
    int tid = threadIdx.x;
    int tx = tid % 16, ty = tid / 16;
    int i0 = blockIdx.x * 64, j0 = blockIdx.y * 64;
    if (tid < 64) su[tid] = uidx[i0 + tid];
    if (tid >= 64 && tid < 128) sv[tid - 64] = vidx[j0 + tid - 64];
    if (tid >= 128 && tid < 138) sa[tid - 128] = a_f[tid - 128];

    float s0a[4][4] = {}, s1a[4][4] = {};
    for (int k0 = 0; k0 < H1; k0 += 64) {
        #pragma unroll
        for (int l = 0; l < 4; l++) {
            int g = tid + l * 256;
            int i = g >> 4, kc = g & 15;
            float4 x0 = *(const float4*)(t01 + (size_t)(i0 + i) * H1 + k0 + kc * 4);
            float4 x1 = *(const float4*)(t01 + (size_t)N4 * H1 + (size_t)(i0 + i) * H1 + k0 + kc * 4);
            float4 xv = *(const float4*)(vh + (size_t)(j0 + i) * H1 + k0 + kc * 4);
            T0s[kc * 4 + 0][i] = x0.x; T0s[kc * 4 + 1][i] = x0.y; T0s[kc * 4 + 2][i] = x0.z; T0s[kc * 4 + 3][i] = x0.w;
            T1s[kc * 4 + 0][i] = x1.x; T1s[kc * 4 + 1][i] = x1.y; T1s[kc * 4 + 2][i] = x1.z; T1s[kc * 4 + 3][i] = x1.w;
            Vs [kc * 4 + 0][i] = xv.x; Vs [kc * 4 + 1][i] = xv.y; Vs [kc * 4 + 2][i] = xv.z; Vs [kc * 4 + 3][i] = xv.w;
        }
        __syncthreads();
        #pragma unroll
        for (int k = 0; k < 64; k++) {
            float a0[4], a1[4], bb[4];
            #pragma unroll
            for (int m = 0; m < 4; m++) { a0[m] = T0s[k][ty * 4 + m]; a1[m] = T1s[k][ty * 4 + m]; }
            #pragma unroll
            for (int n = 0; n < 4; n++) bb[n] = Vs[k][tx * 4 + n];
            #pragma unroll
            for (int m = 0; m < 4; m++)
                #pragma unroll
                for (int n = 0; n < 4; n++) {
                    s0a[m][n] = fmaf(a0[m], bb[n], s0a[m][n]);
                    s1a[m][n] = fmaf(a1[m], bb[n], s1a[m][n]);
                }
        }
        __syncthreads();
    }

    float lsum = 0.f, ssum = 0.f, nobs = 0.f;
    #pragma unroll
    for (int ii = 0; ii < 4; ii++) {
        int ig = i0 + ty * 4 + ii;
        int urow = su[ty * 4 + ii];
        float4 orow;
        float* op = (float*)&orow;
        #pragma unroll
        for (int jj = 0; jj < 4; jj++) {
            float v0 = s0a[ii][jj], v1 = s1a[ii][jj];
            float l[NC];
            float mx = -1e30f;
            #pragma unroll
            for (int c = 0; c < NC; c++) {
                l[c] = sa[c] * v0 + sa[5 + c] * v1;
                mx = fmaxf(mx, l[c]);
            }
            float den = 0.f, num = 0.f;
            #pragma unroll
            for (int c = 0; c < NC; c++) {
                float e = __expf(l[c] - mx);
                den += e;
                num += (float)(c + 1) * e;
            }
            float mh = num / den;
            op[jj] = mh;
            int cb = code[(size_t)urow * N4 + sv[tx * 4 + jj]];
            if (cb) {
                float lse = mx + __logf(den);
                lsum += lse - l[cb - 1];        // = -logp[cb-1]
                float df = mh - (float)cb;
                ssum += df * df;
                nobs += 1.f;
            }
        }
        *(float4*)(mhat + (size_t)ig * N4 + j0 + tx * 4) = orow;
    }
    #pragma unroll
    for (int off = 32; off; off >>= 1) {
        lsum += __shfl_down(lsum, off, 64);
        ssum += __shfl_down(ssum, off, 64);
        nobs += __shfl_down(nobs, off, 64);
    }
    if ((tid & 63) == 0) {
        atomicAdd(accum + 0, lsum);
        atomicAdd(accum + 1, ssum);
        atomicAdd(accum + 2, nobs);
    }
}

// ---------------------------------------------------------------- k_finalize
__global__ void k_finalize(const float* __restrict__ accum, float* __restrict__ out) {
    float n = fmaxf(accum[2], 1.f);
    out[NUV + 0] = accum[0] / n;
    out[NUV + 1] = sqrtf(accum[1] / n);
}

// ================================================================ launch
extern "C" void kernel_launch(void* const* d_in, const int* in_sizes, int n_in,
                              void* d_out, int out_size, void* d_ws, size_t ws_size,
                              hipStream_t stream) {
    const int* u = (const int*)d_in[0];
    const int* v = (const int*)d_in[1];
    // d_in[2] = r (unused by reference)
    const float* adj    = (const float*)d_in[3];
    const float* u_feat = (const float*)d_in[4];
    const float* v_feat = (const float*)d_in[5];
    const float* u_w    = (const float*)d_in[6];
    const float* v_w    = (const float*)d_in[7];
    const float* Wu1    = (const float*)d_in[8];
    const float* bu1    = (const float*)d_in[9];
    const float* Wv1    = (const float*)d_in[10];
    const float* bv1    = (const float*)d_in[11];
    const float* Wu2    = (const float*)d_in[12];
    const float* Wv2    = (const float*)d_in[13];
    const float* P      = (const float*)d_in[14];
    const float* a      = (const float*)d_in[15];
    float* out = (float*)d_out;

    char* ws = (char*)d_ws;
    // workspace layout (bytes; all 256-aligned); total ~112.2 MiB
    const size_t O_CODE  = 0;                        // 16,777,216 u8
    const size_t O_CNTU  = 16777216;                 // 16,384 i32
    const size_t O_CNTV  = O_CNTU + 16384;           // 16,384 i32
    const size_t O_ACC   = O_CNTV + 16384;           // 256 B (loss, se, nobs)
    const size_t O_AU    = O_ACC + 256;              // 20,971,520 f32: cnt_u * cumsum(u_w)
    const size_t O_BV    = O_AU + 20971520;          // 20,971,520 f32
    const size_t O_UNN   = O_BV + 20971520;          // 4,194,304 f32
    const size_t O_VNN   = O_UNN + 4194304;          // 4,194,304 f32
    const size_t O_RDEG  = O_VNN + 4194304;          // 16,384 f32
    const size_t O_CDEG  = O_RDEG + 16384;           // 16,384 f32
    const size_t O_UCAT  = O_CDEG + 16384;           // 12,582,912 f32 [4096][768]
    const size_t O_VCAT  = O_UCAT + 12582912;        // 12,582,912 f32
    const size_t O_UH    = O_VCAT + 12582912;        // 2,097,152 f32
    const size_t O_VH    = O_UH + 2097152;           // 2,097,152 f32
    const size_t O_PT    = O_VH + 2097152;           // 131,072 f32
    const size_t O_T     = O_PT + 131072;            // 4,194,304 f32 [2][4096][128]
    const size_t O_CODET = O_T + 4194304;            // 16,777,216 u8

    uint8_t* code  = (uint8_t*)(ws + O_CODE);
    uint8_t* codeT = (uint8_t*)(ws + O_CODET);
    int* cnt_u = (int*)(ws + O_CNTU);
    int* cnt_v = (int*)(ws + O_CNTV);
    float* accum = (float*)(ws + O_ACC);
    float* A_u = (float*)(ws + O_AU);
    float* B_v = (float*)(ws + O_BV);
    float* u_nn = (float*)(ws + O_UNN);
    float* v_nn = (float*)(ws + O_VNN);
    float* rowDeg = (float*)(ws + O_RDEG);
    float* colDeg = (float*)(ws + O_CDEG);
    float* ucat = (float*)(ws + O_UCAT);
    float* vcat = (float*)(ws + O_VCAT);
    float* uh = (float*)(ws + O_UH);
    float* vh = (float*)(ws + O_VH);
    float* Pt = (float*)(ws + O_PT);
    float* tbuf = (float*)(ws + O_T);

    // zero counters + accumulators (contiguous region)
    hipMemsetAsync(ws + O_CNTU, 0, 16384 + 16384 + 256, stream);

    k_counts<<<16, 256, 0, stream>>>(u, v, cnt_u, cnt_v);
    k_code<<<16384, 256, 0, stream>>>(adj, (uchar4*)code);
    k_transpose<<<dim3(64, 64), 256, 0, stream>>>(code, codeT);
    k_wcumsum<<<N4, 256, 0, stream>>>(u_w, cnt_u, A_u);
    k_wcumsum<<<N4, 256, 0, stream>>>(v_w, cnt_v, B_v);
    // u_nn[p] = sum over q (code row); rowDeg[p]
    k_gather<<<N4, 256, 0, stream>>>(code, B_v, cnt_v, u_nn, rowDeg);
    // v_nn[q] = sum over p (codeT row); colDeg[q]
    k_gather<<<N4, 256, 0, stream>>>(codeT, A_u, cnt_u, v_nn, colDeg);
    // u_z into ucat[:, :256]; v_z into vcat[:, :256]
    k_z<<<N4, 256, 0, stream>>>(u_nn, u, v, colDeg, ucat);
    k_z<<<N4, 256, 0, stream>>>(v_nn, v, u, rowDeg, vcat);
    // u_f = relu(u_features[u] @ Wu1^T + bu1) -> ucat[:, 256:768]
    k_gemm<128, 64, 16, 8, 4, true, true, true>
        <<<dim3(32, 8, 1), 256, 0, stream>>>(u_feat, SIDE, u, Wu1, SIDE, bu1,
                                             ucat + H0, HCAT, SIDE, 0, 0);
    k_gemm<128, 64, 16, 8, 4, true, true, true>
        <<<dim3(32, 8, 1), 256, 0, stream>>>(v_feat, SIDE, v, Wv1, SIDE, bv1,
                                             vcat + H0, HCAT, SIDE, 0, 0);
    // u_h = relu(ucat @ Wu2^T)
    k_gemm<64, 32, 16, 4, 2, false, false, true>
        <<<dim3(64, 4, 1), 256, 0, stream>>>(ucat, HCAT, nullptr, Wu2, HCAT, nullptr,
                                             uh, H1, HCAT, 0, 0);
    k_gemm<64, 32, 16, 4, 2, false, false, true>
        <<<dim3(64, 4, 1), 256, 0, stream>>>(vcat, HCAT, nullptr, Wv2, HCAT, nullptr,
                                             vh, H1, HCAT, 0, 0);
    k_Pt<<<128, 256, 0, stream>>>(P, Pt);
    // t[b] = uh @ P[b]  (as NT with Pt[b][e][d])
    k_gemm<64, 32, 16, 4, 2, false, false, false>
        <<<dim3(64, 4, 2), 256, 0, stream>>>(uh, H1, nullptr, Pt, H1, nullptr,
                                             tbuf, H1, H1, (size_t)H1 * H1, (size_t)N4 * H1);
    k_scores<<<dim3(64, 64), 256, 0, stream>>>(tbuf, vh, code, u, v, a, out, accum);
    k_finalize<<<1, 1, 0, stream>>>(accum, out);
}

// Round 3
// 2201.974 us; speedup vs baseline: 1.5167x; 1.5167x over previous
//
#include <hip/hip_runtime.h>
#include <stdint.h>

// Problem constants
#define N4   4096
#define H0   256
#define SIDE 1024
#define DIN  512
#define HCAT 768      // H0 + DIN
#define H1   128
#define NC   5
#define NUV  16777216ULL   // 4096*4096
#define CAP  1536          // max compacted entries per row (mean ~1024, sigma ~28)

// ---------------------------------------------------------------- k_counts
__global__ __launch_bounds__(256) void k_counts(const int* __restrict__ u,
                                                const int* __restrict__ v,
                                                int* __restrict__ cu,
                                                int* __restrict__ cv) {
    int i = blockIdx.x * 256 + threadIdx.x;   // 4096 threads
    atomicAdd(&cu[u[i]], 1);
    atomicAdd(&cv[v[i]], 1);
}

// ---------------------------------------------------------------- k_code
// code[p][q] = c+1 where adj[c][p][q] != 0 (at most one c), else 0
__global__ __launch_bounds__(256) void k_code(const float* __restrict__ adj,
                                              uchar4* __restrict__ code4) {
    size_t g = (size_t)blockIdx.x * 256 + threadIdx.x;   // unit of 4 elems
    size_t base = g * 4;
    uchar4 out = {0, 0, 0, 0};
    #pragma unroll
    for (int c = 0; c < NC; c++) {
        float4 s = *(const float4*)(adj + (size_t)c * NUV + base);
        out.x = (s.x != 0.f) ? (unsigned char)(c + 1) : out.x;
        out.y = (s.y != 0.f) ? (unsigned char)(c + 1) : out.y;
        out.z = (s.z != 0.f) ? (unsigned char)(c + 1) : out.z;
        out.w = (s.w != 0.f) ? (unsigned char)(c + 1) : out.w;
    }
    code4[g] = out;
}

// ---------------------------------------------------------------- k_transpose (byte, 64x64 tiles)
__global__ __launch_bounds__(256) void k_transpose(const uint8_t* __restrict__ src,
                                                   uint8_t* __restrict__ dst) {
    __shared__ __align__(16) uint8_t tile[64][80];
    int t = threadIdx.x;
    int row = t >> 2;            // 0..63
    int seg = (t & 3) * 16;      // 0,16,32,48
    int p0 = blockIdx.y * 64, q0 = blockIdx.x * 64;
    uint4 vdat = *(const uint4*)(src + (size_t)(p0 + row) * N4 + q0 + seg);
    *(uint4*)(&tile[row][seg]) = vdat;
    __syncthreads();
    union { uint4 u4; uint8_t b[16]; } o;
    #pragma unroll
    for (int l = 0; l < 16; l++) o.b[l] = tile[seg + l][row];
    *(uint4*)(dst + (size_t)(q0 + row) * N4 + p0 + seg) = o.u4;
}

// ---------------------------------------------------------------- k_wcumsum
// out[r][node][h] = f16( cnt[node] * cumsum_r(w)[r][node][h] )
__global__ __launch_bounds__(256) void k_wcumsum(const float* __restrict__ w,
                                                 const int* __restrict__ cnt,
                                                 unsigned short* __restrict__ out) {
    int node = blockIdx.x, h = threadIdx.x;
    float c = (float)cnt[node];
    float acc = 0.f;
    #pragma unroll
    for (int r = 0; r < NC; r++) {
        size_t idx = ((size_t)r * N4 + node) * H0 + h;
        acc += w[idx];
        union { _Float16 h16; unsigned short s; } cvt;
        cvt.h16 = (_Float16)(acc * c);
        out[idx] = cvt.s;
    }
}

// ---------------------------------------------------------------- k_compact
// Compact one code row into entry list (ushort: (r-1)*4096+q), plus
// deg[p] = sum over hits of cntOther[q] and nnz[p].
__global__ __launch_bounds__(256) void k_compact(const uint8_t* __restrict__ codeRows,
                                                 const int* __restrict__ cntOther,
                                                 unsigned short* __restrict__ idx,
                                                 int* __restrict__ nnz,
                                                 float* __restrict__ deg) {
    __shared__ float cw[4096];                 // 16 KB
    __shared__ int scan[256];
    __shared__ unsigned short ebuf[CAP];
    __shared__ float dred[256];
    int p = blockIdx.x, t = threadIdx.x;
    // stage other-side counts as float
    const int4* co4 = (const int4*)cntOther;
    #pragma unroll
    for (int l = 0; l < 4; l++) {
        int4 ci = co4[t + l * 256];
        ((float4*)cw)[t + l * 256] =
            make_float4((float)ci.x, (float)ci.y, (float)ci.z, (float)ci.w);
    }
    // 16 code bytes per thread (registers)
    uint4 w = ((const uint4*)(codeRows + (size_t)p * N4))[t];
    unsigned char b[16];
    __builtin_memcpy(b, &w, 16);
    int cnt = 0;
    #pragma unroll
    for (int j = 0; j < 16; j++) cnt += (b[j] != 0);
    scan[t] = cnt;
    __syncthreads();
    // Hillis-Steele inclusive scan over 256 counts
    for (int off = 1; off < 256; off <<= 1) {
        int val = scan[t];
        int add = (t >= off) ? scan[t - off] : 0;
        __syncthreads();
        scan[t] = val + add;
        __syncthreads();
    }
    int total = scan[255];
    int pos = scan[t] - cnt;   // exclusive prefix
    float dsum = 0.f;
    #pragma unroll
    for (int j = 0; j < 16; j++) {
        int r = b[j];
        if (r) {
            int q = t * 16 + j;
            if (pos < CAP) ebuf[pos] = (unsigned short)((r - 1) * N4 + q);
            pos++;
            dsum += cw[q];
        }
    }
    dred[t] = dsum;
    __syncthreads();
    for (int off = 128; off >= 1; off >>= 1) {
        if (t < off) dred[t] += dred[t + off];
        __syncthreads();
    }
    int tw = total < CAP ? total : CAP;
    if (t == 0) { deg[p] = dred[0]; nnz[p] = tw; }
    for (int e = t; e < tw; e += 256) idx[(size_t)p * CAP + e] = ebuf[e];
}

// ---------------------------------------------------------------- k_gather2
// outNN[p][h] = sum over compacted entries of f16 table row [entry][h]
__global__ __launch_bounds__(256) void k_gather2(const unsigned short* __restrict__ idx,
                                                 const int* __restrict__ nnz,
                                                 const unsigned short* __restrict__ tbl,
                                                 float* __restrict__ outNN) {
    __shared__ unsigned short sidx[256];
    __shared__ float red[512];
    int p = blockIdx.x, t = threadIdx.x;
    int n = nnz[p];
    int half = t >> 7, hp = t & 127;
    const char* tb = (const char*)tbl;
    const unsigned short* rowIdx = idx + (size_t)p * CAP;
    float a0 = 0.f, a1 = 0.f;
    for (int base = 0; base < n; base += 256) {
        int m = n - base; if (m > 256) m = 256;
        if (t < m) sidx[t] = rowIdx[base + t];
        __syncthreads();
        for (int e = half; e < m; e += 2) {
            int off = ((int)sidx[e]) << 9;          // *512 bytes per table row
            unsigned d = *(const unsigned*)(tb + off + hp * 4);
            union { unsigned u; _Float16 h[2]; } cv; cv.u = d;
            a0 += (float)cv.h[0];
            a1 += (float)cv.h[1];
        }
        __syncthreads();
    }
    red[t] = a0; red[256 + t] = a1;
    __syncthreads();
    if (t < 128) {
        float r0 = red[t] + red[128 + t];
        float r1 = red[256 + t] + red[384 + t];
        *(float2*)(outNN + (size_t)p * H0 + 2 * hp) = make_float2(r0, r1);
    }
}

// ---------------------------------------------------------------- k_z
// cat[i][h] = relu(nn[idxs[i]][h] / deg[idxo[i]])  (0 when deg==0)
__global__ __launch_bounds__(256) void k_z(const float* __restrict__ nn,
                                           const int* __restrict__ idxs,
                                           const int* __restrict__ idxo,
                                           const float* __restrict__ deg,
                                           float* __restrict__ cat) {
    int i = blockIdx.x, h = threadIdx.x;
    float d = deg[idxo[i]];
    float inv = d > 0.f ? 1.f / d : 0.f;
    float val = nn[(size_t)idxs[i] * H0 + h] * inv;
    cat[(size_t)i * HCAT + h] = fmaxf(val, 0.f);
}

// ---------------------------------------------------------------- generic NT GEMM (fp32)
template <int TM, int TN, int BK, int RM, int RN, bool GATHER, bool BIAS, bool RELU>
__global__ __launch_bounds__(256) void k_gemm(const float* __restrict__ A, int lda,
                                              const int* __restrict__ rowmap,
                                              const float* __restrict__ B, int ldb,
                                              const float* __restrict__ bias,
                                              float* __restrict__ C, int ldc, int K,
                                              size_t bzs, size_t czs) {
    constexpr int TX = TN / RN;
    constexpr int TY = TM / RM;
    static_assert(TX * TY == 256, "block must be 256");
    __shared__ float As[BK][TM + 4];
    __shared__ float Bs[BK][TN + 4];
    int tid = threadIdx.x;
    int tx = tid % TX, ty = tid / TX;
    int i0 = blockIdx.x * TM, n0 = blockIdx.y * TN;
    const float* Bz = B + (size_t)blockIdx.z * bzs;
    float acc[RM][RN] = {};
    for (int k0 = 0; k0 < K; k0 += BK) {
        for (int g = tid; g < TM * BK / 4; g += 256) {
            int i = g / (BK / 4), kc = g % (BK / 4);
            int row = GATHER ? rowmap[i0 + i] : (i0 + i);
            float4 val = *(const float4*)(A + (size_t)row * lda + k0 + kc * 4);
            As[kc * 4 + 0][i] = val.x; As[kc * 4 + 1][i] = val.y;
            As[kc * 4 + 2][i] = val.z; As[kc * 4 + 3][i] = val.w;
        }
        for (int g = tid; g < TN * BK / 4; g += 256) {
            int n = g / (BK / 4), kc = g % (BK / 4);
            float4 val = *(const float4*)(Bz + (size_t)(n0 + n) * ldb + k0 + kc * 4);
            Bs[kc * 4 + 0][n] = val.x; Bs[kc * 4 + 1][n] = val.y;
            Bs[kc * 4 + 2][n] = val.z; Bs[kc * 4 + 3][n] = val.w;
        }
        __syncthreads();
        #pragma unroll
        for (int k = 0; k < BK; k++) {
            float av[RM], bv[RN];
            #pragma unroll
            for (int m = 0; m < RM; m++) av[m] = As[k][ty * RM + m];
            #pragma unroll
            for (int n = 0; n < RN; n++) bv[n] = Bs[k][tx * RN + n];
            #pragma unroll
            for (int m = 0; m < RM; m++)
                #pragma unroll
                for (int n = 0; n < RN; n++)
                    acc[m][n] = fmaf(av[m], bv[n], acc[m][n]);
        }
        __syncthreads();
    }
    float* Cz = C + (size_t)blockIdx.z * czs;
    #pragma unroll
    for (int m = 0; m < RM; m++) {
        int ig = i0 + ty * RM + m;
        #pragma unroll
        for (int n = 0; n < RN; n++) {
            float vv = acc[m][n];
            if (BIAS) vv += bias[n0 + tx * RN + n];
            if (RELU) vv = fmaxf(vv, 0.f);
            Cz[(size_t)ig * ldc + n0 + tx * RN + n] = vv;
        }
    }
}

// ---------------------------------------------------------------- k_Pt : Pt[b][e][d] = P[b][d][e]
__global__ __launch_bounds__(256) void k_Pt(const float* __restrict__ P, float* __restrict__ Pt) {
    int tid = blockIdx.x * 256 + threadIdx.x;   // 32768
    int b = tid >> 14;
    int d = (tid >> 7) & 127;
    int e = tid & 127;
    Pt[((size_t)b * 128 + e) * 128 + d] = P[tid];
}

// ---------------------------------------------------------------- k_scores (fused decoder+softmax+reductions)
__global__ __launch_bounds__(256) void k_scores(const float* __restrict__ t01,   // [2][4096][128]
                                                const float* __restrict__ vh,    // [4096][128]
                                                const uint8_t* __restrict__ code,
                                                const int* __restrict__ uidx,
                                                const int* __restrict__ vidx,
                                                const float* __restrict__ a_f,   // [2][5]
                                                float* __restrict__ mhat,        // [4096][4096]
                                                float* __restrict__ accum) {     // loss, se, nobs
    __shared__ float T0s[64][68], T1s[64][68], Vs[64][68];
    __shared__ int su[64], sv[64];
    __shared__ float sa[16];
    int tid = threadIdx.x;
    int tx = tid % 16, ty = tid / 16;
    int i0 = blockIdx.x * 64, j0 = blockIdx.y * 64;
    if (tid < 64) su[tid] = uidx[i0 + tid];
    if (tid >= 64 && tid < 128) sv[tid - 64] = vidx[j0 + tid - 64];
    if (tid >= 128 && tid < 138) sa[tid - 128] = a_f[tid - 128];

    float s0a[4][4] = {}, s1a[4][4] = {};
    for (int k0 = 0; k0 < H1; k0 += 64) {
        #pragma unroll
        for (int l = 0; l < 4; l++) {
            int g = tid + l * 256;
            int i = g >> 4, kc = g & 15;
            float4 x0 = *(const float4*)(t01 + (size_t)(i0 + i) * H1 + k0 + kc * 4);
            float4 x1 = *(const float4*)(t01 + (size_t)N4 * H1 + (size_t)(i0 + i) * H1 + k0 + kc * 4);
            float4 xv = *(const float4*)(vh + (size_t)(j0 + i) * H1 + k0 + kc * 4);
            T0s[kc * 4 + 0][i] = x0.x; T0s[kc * 4 + 1][i] = x0.y; T0s[kc * 4 + 2][i] = x0.z; T0s[kc * 4 + 3][i] = x0.w;
            T1s[kc * 4 + 0][i] = x1.x; T1s[kc * 4 + 1][i] = x1.y; T1s[kc * 4 + 2][i] = x1.z; T1s[kc * 4 + 3][i] = x1.w;
            Vs [kc * 4 + 0][i] = xv.x; Vs [kc * 4 + 1][i] = xv.y; Vs [kc * 4 + 2][i] = xv.z; Vs [kc * 4 + 3][i] = xv.w;
        }
        __syncthreads();
        #pragma unroll
        for (int k = 0; k < 64; k++) {
            float a0[4], a1[4], bb[4];
            #pragma unroll
            for (int m = 0; m < 4; m++) { a0[m] = T0s[k][ty * 4 + m]; a1[m] = T1s[k][ty * 4 + m]; }
            #pragma unroll
            for (int n = 0; n < 4; n++) bb[n] = Vs[k][tx * 4 + n];
            #pragma unroll
            for (int m = 0; m < 4; m++)
                #pragma unroll
                for (int n = 0; n < 4; n++) {
                    s0a[m][n] = fmaf(a0[m], bb[n], s0a[m][n]);
                    s1a[m][n] = fmaf(a1[m], bb[n], s1a[m][n]);
                }
        }
        __syncthreads();
    }

    float lsum = 0.f, ssum = 0.f, nobs = 0.f;
    #pragma unroll
    for (int ii = 0; ii < 4; ii++) {
        int ig = i0 + ty * 4 + ii;
        int urow = su[ty * 4 + ii];
        float4 orow;
        float* op = (float*)&orow;
        #pragma unroll
        for (int jj = 0; jj < 4; jj++) {
            float v0 = s0a[ii][jj], v1 = s1a[ii][jj];
            float l[NC];
            float mx = -1e30f;
            #pragma unroll
            for (int c = 0; c < NC; c++) {
                l[c] = sa[c] * v0 + sa[5 + c] * v1;
                mx = fmaxf(mx, l[c]);
            }
            float den = 0.f, num = 0.f;
            #pragma unroll
            for (int c = 0; c < NC; c++) {
                float e = __expf(l[c] - mx);
                den += e;
                num += (float)(c + 1) * e;
            }
            float mh = num / den;
            op[jj] = mh;
            int cb = code[(size_t)urow * N4 + sv[tx * 4 + jj]];
            if (cb) {
                float lse = mx + __logf(den);
                lsum += lse - l[cb - 1];        // = -logp[cb-1]
                float df = mh - (float)cb;
                ssum += df * df;
                nobs += 1.f;
            }
        }
        *(float4*)(mhat + (size_t)ig * N4 + j0 + tx * 4) = orow;
    }
    #pragma unroll
    for (int off = 32; off; off >>= 1) {
        lsum += __shfl_down(lsum, off, 64);
        ssum += __shfl_down(ssum, off, 64);
        nobs += __shfl_down(nobs, off, 64);
    }
    if ((tid & 63) == 0) {
        atomicAdd(accum + 0, lsum);
        atomicAdd(accum + 1, ssum);
        atomicAdd(accum + 2, nobs);
    }
}

// ---------------------------------------------------------------- k_finalize
__global__ void k_finalize(const float* __restrict__ accum, float* __restrict__ out) {
    float n = fmaxf(accum[2], 1.f);
    out[NUV + 0] = accum[0] / n;
    out[NUV + 1] = sqrtf(accum[1] / n);
}

// ================================================================ launch
extern "C" void kernel_launch(void* const* d_in, const int* in_sizes, int n_in,
                              void* d_out, int out_size, void* d_ws, size_t ws_size,
                              hipStream_t stream) {
    const int* u = (const int*)d_in[0];
    const int* v = (const int*)d_in[1];
    const float* adj    = (const float*)d_in[3];
    const float* u_feat = (const float*)d_in[4];
    const float* v_feat = (const float*)d_in[5];
    const float* u_w    = (const float*)d_in[6];
    const float* v_w    = (const float*)d_in[7];
    const float* Wu1    = (const float*)d_in[8];
    const float* bu1    = (const float*)d_in[9];
    const float* Wv1    = (const float*)d_in[10];
    const float* bv1    = (const float*)d_in[11];
    const float* Wu2    = (const float*)d_in[12];
    const float* Wv2    = (const float*)d_in[13];
    const float* P      = (const float*)d_in[14];
    const float* a      = (const float*)d_in[15];
    float* out = (float*)d_out;

    char* ws = (char*)d_ws;
    // workspace layout (bytes); total ~105 MB. codeT overlays UCAT/VCAT
    // (codeT dead after k_compact; UCAT/VCAT written from k_z onward).
    const size_t O_CODE  = 0;                         // 16,777,216 u8
    const size_t O_CNTU  = 16777216;                  // 16,384 i32
    const size_t O_CNTV  = O_CNTU + 16384;            // 16,384 i32
    const size_t O_ACC   = O_CNTV + 16384;            // 256 B
    const size_t O_TAU   = O_ACC + 256;               // 10,485,760 f16 table (u side)
    const size_t O_TBV   = O_TAU + 10485760;          // 10,485,760 f16 table (v side)
    const size_t O_IDXU  = O_TBV + 10485760;          // 12,582,912 u16 [4096][CAP]
    const size_t O_IDXV  = O_IDXU + 12582912;         // 12,582,912 u16
    const size_t O_NNZU  = O_IDXV + 12582912;         // 16,384 i32
    const size_t O_NNZV  = O_NNZU + 16384;            // 16,384 i32
    const size_t O_RDEG  = O_NNZV + 16384;            // 16,384 f32
    const size_t O_CDEG  = O_RDEG + 16384;            // 16,384 f32
    const size_t O_UNN   = O_CDEG + 16384;            // 4,194,304 f32
    const size_t O_VNN   = O_UNN + 4194304;           // 4,194,304 f32
    const size_t O_UCAT  = O_VNN + 4194304;           // 12,582,912 f32 [4096][768]
    const size_t O_VCAT  = O_UCAT + 12582912;         // 12,582,912 f32
    const size_t O_UH    = O_VCAT + 12582912;         // 2,097,152 f32
    const size_t O_VH    = O_UH + 2097152;            // 2,097,152 f32
    const size_t O_PT    = O_VH + 2097152;            // 131,072 f32
    const size_t O_T     = O_PT + 131072;             // 4,194,304 f32 [2][4096][128]
    const size_t O_CODET = O_UCAT;                    // overlay: 16,777,216 u8

    uint8_t* code  = (uint8_t*)(ws + O_CODE);
    uint8_t* codeT = (uint8_t*)(ws + O_CODET);
    int* cnt_u = (int*)(ws + O_CNTU);
    int* cnt_v = (int*)(ws + O_CNTV);
    float* accum = (float*)(ws + O_ACC);
    unsigned short* T_Au = (unsigned short*)(ws + O_TAU);
    unsigned short* T_Bv = (unsigned short*)(ws + O_TBV);
    unsigned short* idxU = (unsigned short*)(ws + O_IDXU);
    unsigned short* idxV = (unsigned short*)(ws + O_IDXV);
    int* nnzU = (int*)(ws + O_NNZU);
    int* nnzV = (int*)(ws + O_NNZV);
    float* rowDeg = (float*)(ws + O_RDEG);
    float* colDeg = (float*)(ws + O_CDEG);
    float* u_nn = (float*)(ws + O_UNN);
    float* v_nn = (float*)(ws + O_VNN);
    float* ucat = (float*)(ws + O_UCAT);
    float* vcat = (float*)(ws + O_VCAT);
    float* uh = (float*)(ws + O_UH);
    float* vh = (float*)(ws + O_VH);
    float* Pt = (float*)(ws + O_PT);
    float* tbuf = (float*)(ws + O_T);

    hipMemsetAsync(ws + O_CNTU, 0, 16384 + 16384 + 256, stream);

    k_counts<<<16, 256, 0, stream>>>(u, v, cnt_u, cnt_v);
    k_code<<<16384, 256, 0, stream>>>(adj, (uchar4*)code);
    k_transpose<<<dim3(64, 64), 256, 0, stream>>>(code, codeT);
    k_wcumsum<<<N4, 256, 0, stream>>>(u_w, cnt_u, T_Au);
    k_wcumsum<<<N4, 256, 0, stream>>>(v_w, cnt_v, T_Bv);
    // u-direction: compact code rows; deg = rowDeg (weights cnt_v)
    k_compact<<<N4, 256, 0, stream>>>(code, cnt_v, idxU, nnzU, rowDeg);
    // v-direction: compact codeT rows; deg = colDeg (weights cnt_u)
    k_compact<<<N4, 256, 0, stream>>>(codeT, cnt_u, idxV, nnzV, colDeg);
    k_gather2<<<N4, 256, 0, stream>>>(idxU, nnzU, T_Bv, u_nn);
    k_gather2<<<N4, 256, 0, stream>>>(idxV, nnzV, T_Au, v_nn);
    // u_z into ucat[:, :256]; v_z into vcat[:, :256]
    k_z<<<N4, 256, 0, stream>>>(u_nn, u, v, colDeg, ucat);
    k_z<<<N4, 256, 0, stream>>>(v_nn, v, u, rowDeg, vcat);
    // u_f = relu(u_features[u] @ Wu1^T + bu1) -> ucat[:, 256:768]
    k_gemm<128, 64, 16, 8, 4, true, true, true>
        <<<dim3(32, 8, 1), 256, 0, stream>>>(u_feat, SIDE, u, Wu1, SIDE, bu1,
                                             ucat + H0, HCAT, SIDE, 0, 0);
    k_gemm<128, 64, 16, 8, 4, true, true, true>
        <<<dim3(32, 8, 1), 256, 0, stream>>>(v_feat, SIDE, v, Wv1, SIDE, bv1,
                                             vcat + H0, HCAT, SIDE, 0, 0);
    // u_h = relu(ucat @ Wu2^T)
    k_gemm<64, 32, 16, 4, 2, false, false, true>
        <<<dim3(64, 4, 1), 256, 0, stream>>>(ucat, HCAT, nullptr, Wu2, HCAT, nullptr,
                                             uh, H1, HCAT, 0, 0);
    k_gemm<64, 32, 16, 4, 2, false, false, true>
        <<<dim3(64, 4, 1), 256, 0, stream>>>(vcat, HCAT, nullptr, Wv2, HCAT, nullptr,
                                             vh, H1, HCAT, 0, 0);
    k_Pt<<<128, 256, 0, stream>>>(P, Pt);
    // t[b] = uh @ P[b]  (as NT with Pt[b][e][d])
    k_gemm<64, 32, 16, 4, 2, false, false, false>
        <<<dim3(64, 4, 2), 256, 0, stream>>>(uh, H1, nullptr, Pt, H1, nullptr,
                                             tbuf, H1, H1, (size_t)H1 * H1, (size_t)N4 * H1);
    k_scores<<<dim3(64, 64), 256, 0, stream>>>(tbuf, vh, code, u, v, a, out, accum);
    k_finalize<<<1, 1, 0, stream>>>(accum, out);
}

// Round 4
// 1905.754 us; speedup vs baseline: 1.7525x; 1.1554x over previous
//
#include <hip/hip_runtime.h>
#include <stdint.h>

// Problem constants
#define N4   4096
#define H0   256
#define SIDE 1024
#define DIN  512
#define HCAT 768      // H0 + DIN
#define H1   128
#define NC   5
#define NUV  16777216ULL   // 4096*4096
#define CAP  1536          // max compacted entries per row

// ---------------------------------------------------------------- k_counts
__global__ __launch_bounds__(256) void k_counts(const int* __restrict__ u,
                                                const int* __restrict__ v,
                                                int* __restrict__ cu,
                                                int* __restrict__ cv) {
    int i = blockIdx.x * 256 + threadIdx.x;   // 4096 threads
    atomicAdd(&cu[u[i]], 1);
    atomicAdd(&cv[v[i]], 1);
}

// ---------------------------------------------------------------- k_code
// code[p][q] = c+1 where adj[c][p][q] != 0 (at most one c), else 0
__global__ __launch_bounds__(256) void k_code(const float* __restrict__ adj,
                                              uchar4* __restrict__ code4) {
    size_t g = (size_t)blockIdx.x * 256 + threadIdx.x;   // unit of 4 elems
    size_t base = g * 4;
    uchar4 out = {0, 0, 0, 0};
    #pragma unroll
    for (int c = 0; c < NC; c++) {
        float4 s = *(const float4*)(adj + (size_t)c * NUV + base);
        out.x = (s.x != 0.f) ? (unsigned char)(c + 1) : out.x;
        out.y = (s.y != 0.f) ? (unsigned char)(c + 1) : out.y;
        out.z = (s.z != 0.f) ? (unsigned char)(c + 1) : out.z;
        out.w = (s.w != 0.f) ? (unsigned char)(c + 1) : out.w;
    }
    code4[g] = out;
}

// ---------------------------------------------------------------- k_transpose (byte, 64x64 tiles)
__global__ __launch_bounds__(256) void k_transpose(const uint8_t* __restrict__ src,
                                                   uint8_t* __restrict__ dst) {
    __shared__ __align__(16) uint8_t tile[64][80];
    int t = threadIdx.x;
    int row = t >> 2;            // 0..63
    int seg = (t & 3) * 16;      // 0,16,32,48
    int p0 = blockIdx.y * 64, q0 = blockIdx.x * 64;
    uint4 vdat = *(const uint4*)(src + (size_t)(p0 + row) * N4 + q0 + seg);
    *(uint4*)(&tile[row][seg]) = vdat;
    __syncthreads();
    union { uint4 u4; uint8_t b[16]; } o;
    #pragma unroll
    for (int l = 0; l < 16; l++) o.b[l] = tile[seg + l][row];
    *(uint4*)(dst + (size_t)(q0 + row) * N4 + p0 + seg) = o.u4;
}

// ---------------------------------------------------------------- k_wcumsum
// out[r][node][h] = f16( cnt[node] * cumsum_r(w)[r][node][h] )
__global__ __launch_bounds__(256) void k_wcumsum(const float* __restrict__ w,
                                                 const int* __restrict__ cnt,
                                                 unsigned short* __restrict__ out) {
    int node = blockIdx.x, h = threadIdx.x;
    float c = (float)cnt[node];
    float acc = 0.f;
    #pragma unroll
    for (int r = 0; r < NC; r++) {
        size_t idx = ((size_t)r * N4 + node) * H0 + h;
        acc += w[idx];
        union { _Float16 h16; unsigned short s; } cvt;
        cvt.h16 = (_Float16)(acc * c);
        out[idx] = cvt.s;
    }
}

// ---------------------------------------------------------------- k_compact
// Compact one code row into entry list (ushort: (r-1)*4096+q), plus
// deg[p] = sum over hits of cntOther[q] and nnz[p].
__global__ __launch_bounds__(256) void k_compact(const uint8_t* __restrict__ codeRows,
                                                 const int* __restrict__ cntOther,
                                                 unsigned short* __restrict__ idx,
                                                 int* __restrict__ nnz,
                                                 float* __restrict__ deg) {
    __shared__ float cw[4096];                 // 16 KB
    __shared__ int scan[256];
    __shared__ unsigned short ebuf[CAP];
    __shared__ float dred[256];
    int p = blockIdx.x, t = threadIdx.x;
    const int4* co4 = (const int4*)cntOther;
    #pragma unroll
    for (int l = 0; l < 4; l++) {
        int4 ci = co4[t + l * 256];
        ((float4*)cw)[t + l * 256] =
            make_float4((float)ci.x, (float)ci.y, (float)ci.z, (float)ci.w);
    }
    uint4 w = ((const uint4*)(codeRows + (size_t)p * N4))[t];
    unsigned char b[16];
    __builtin_memcpy(b, &w, 16);
    int cnt = 0;
    #pragma unroll
    for (int j = 0; j < 16; j++) cnt += (b[j] != 0);
    scan[t] = cnt;
    __syncthreads();
    for (int off = 1; off < 256; off <<= 1) {
        int val = scan[t];
        int add = (t >= off) ? scan[t - off] : 0;
        __syncthreads();
        scan[t] = val + add;
        __syncthreads();
    }
    int total = scan[255];
    int pos = scan[t] - cnt;   // exclusive prefix
    float dsum = 0.f;
    #pragma unroll
    for (int j = 0; j < 16; j++) {
        int r = b[j];
        if (r) {
            int q = t * 16 + j;
            if (pos < CAP) ebuf[pos] = (unsigned short)((r - 1) * N4 + q);
            pos++;
            dsum += cw[q];
        }
    }
    dred[t] = dsum;
    __syncthreads();
    for (int off = 128; off >= 1; off >>= 1) {
        if (t < off) dred[t] += dred[t + off];
        __syncthreads();
    }
    int tw = total < CAP ? total : CAP;
    if (t == 0) { deg[p] = dred[0]; nnz[p] = tw; }
    for (int e = t; e < tw; e += 256) idx[(size_t)p * CAP + e] = ebuf[e];
}

// ---------------------------------------------------------------- k_gather2
// outNN[p][h] = sum over compacted entries of f16 table row [entry][h]
__global__ __launch_bounds__(256) void k_gather2(const unsigned short* __restrict__ idx,
                                                 const int* __restrict__ nnz,
                                                 const unsigned short* __restrict__ tbl,
                                                 float* __restrict__ outNN) {
    __shared__ unsigned short sidx[256];
    __shared__ float red[512];
    int p = blockIdx.x, t = threadIdx.x;
    int n = nnz[p];
    int half = t >> 7, hp = t & 127;
    const char* tb = (const char*)tbl;
    const unsigned short* rowIdx = idx + (size_t)p * CAP;
    float a0 = 0.f, a1 = 0.f;
    for (int base = 0; base < n; base += 256) {
        int m = n - base; if (m > 256) m = 256;
        if (t < m) sidx[t] = rowIdx[base + t];
        __syncthreads();
        for (int e = half; e < m; e += 2) {
            int off = ((int)sidx[e]) << 9;          // *512 bytes per table row
            unsigned d = *(const unsigned*)(tb + off + hp * 4);
            union { unsigned u; _Float16 h[2]; } cv; cv.u = d;
            a0 += (float)cv.h[0];
            a1 += (float)cv.h[1];
        }
        __syncthreads();
    }
    red[t] = a0; red[256 + t] = a1;
    __syncthreads();
    if (t < 128) {
        float r0 = red[t] + red[128 + t];
        float r1 = red[256 + t] + red[384 + t];
        *(float2*)(outNN + (size_t)p * H0 + 2 * hp) = make_float2(r0, r1);
    }
}

// ---------------------------------------------------------------- k_reorder
// codeR[i][j] = code[u[i]][v[j]]  (LDS row staging; coalesced global IO)
__global__ __launch_bounds__(256) void k_reorder(const uint8_t* __restrict__ code,
                                                 const int* __restrict__ u,
                                                 const int* __restrict__ v,
                                                 uint8_t* __restrict__ codeR) {
    __shared__ __align__(16) uint8_t rowbuf[4096];
    int i = blockIdx.x, t = threadIdx.x;
    int urow = u[i];
    ((uint4*)rowbuf)[t] = ((const uint4*)(code + (size_t)urow * N4))[t];
    __syncthreads();
    uint8_t ob[16];
    #pragma unroll
    for (int w = 0; w < 4; w++) {
        int4 vv = ((const int4*)v)[t * 4 + w];
        ob[w * 4 + 0] = rowbuf[vv.x];
        ob[w * 4 + 1] = rowbuf[vv.y];
        ob[w * 4 + 2] = rowbuf[vv.z];
        ob[w * 4 + 3] = rowbuf[vv.w];
    }
    uint4 o;
    __builtin_memcpy(&o, ob, 16);
    ((uint4*)(codeR + (size_t)i * N4))[t] = o;
}

// ---------------------------------------------------------------- k_z
// cat[i][h] = relu(nn[idxs[i]][h] / deg[idxo[i]])  (0 when deg==0)
__global__ __launch_bounds__(256) void k_z(const float* __restrict__ nn,
                                           const int* __restrict__ idxs,
                                           const int* __restrict__ idxo,
                                           const float* __restrict__ deg,
                                           float* __restrict__ cat) {
    int i = blockIdx.x, h = threadIdx.x;
    float d = deg[idxo[i]];
    float inv = d > 0.f ? 1.f / d : 0.f;
    float val = nn[(size_t)idxs[i] * H0 + h] * inv;
    cat[(size_t)i * HCAT + h] = fmaxf(val, 0.f);
}

// ---------------------------------------------------------------- generic NT GEMM (fp32)
template <int TM, int TN, int BK, int RM, int RN, bool GATHER, bool BIAS, bool RELU>
__global__ __launch_bounds__(256) void k_gemm(const float* __restrict__ A, int lda,
                                              const int* __restrict__ rowmap,
                                              const float* __restrict__ B, int ldb,
                                              const float* __restrict__ bias,
                                              float* __restrict__ C, int ldc, int K,
                                              size_t bzs, size_t czs) {
    constexpr int TX = TN / RN;
    constexpr int TY = TM / RM;
    static_assert(TX * TY == 256, "block must be 256");
    __shared__ float As[BK][TM + 4];
    __shared__ float Bs[BK][TN + 4];
    int tid = threadIdx.x;
    int tx = tid % TX, ty = tid / TX;
    int i0 = blockIdx.x * TM, n0 = blockIdx.y * TN;
    const float* Bz = B + (size_t)blockIdx.z * bzs;
    float acc[RM][RN] = {};
    for (int k0 = 0; k0 < K; k0 += BK) {
        for (int g = tid; g < TM * BK / 4; g += 256) {
            int i = g / (BK / 4), kc = g % (BK / 4);
            int row = GATHER ? rowmap[i0 + i] : (i0 + i);
            float4 val = *(const float4*)(A + (size_t)row * lda + k0 + kc * 4);
            As[kc * 4 + 0][i] = val.x; As[kc * 4 + 1][i] = val.y;
            As[kc * 4 + 2][i] = val.z; As[kc * 4 + 3][i] = val.w;
        }
        for (int g = tid; g < TN * BK / 4; g += 256) {
            int n = g / (BK / 4), kc = g % (BK / 4);
            float4 val = *(const float4*)(Bz + (size_t)(n0 + n) * ldb + k0 + kc * 4);
            Bs[kc * 4 + 0][n] = val.x; Bs[kc * 4 + 1][n] = val.y;
            Bs[kc * 4 + 2][n] = val.z; Bs[kc * 4 + 3][n] = val.w;
        }
        __syncthreads();
        #pragma unroll
        for (int k = 0; k < BK; k++) {
            float av[RM], bv[RN];
            #pragma unroll
            for (int m = 0; m < RM; m++) av[m] = As[k][ty * RM + m];
            #pragma unroll
            for (int n = 0; n < RN; n++) bv[n] = Bs[k][tx * RN + n];
            #pragma unroll
            for (int m = 0; m < RM; m++)
                #pragma unroll
                for (int n = 0; n < RN; n++)
                    acc[m][n] = fmaf(av[m], bv[n], acc[m][n]);
        }
        __syncthreads();
    }
    float* Cz = C + (size_t)blockIdx.z * czs;
    #pragma unroll
    for (int m = 0; m < RM; m++) {
        int ig = i0 + ty * RM + m;
        #pragma unroll
        for (int n = 0; n < RN; n++) {
            float vv = acc[m][n];
            if (BIAS) vv += bias[n0 + tx * RN + n];
            if (RELU) vv = fmaxf(vv, 0.f);
            Cz[(size_t)ig * ldc + n0 + tx * RN + n] = vv;
        }
    }
}

// ---------------------------------------------------------------- k_Pt : Pt[b][e][d] = P[b][d][e]
__global__ __launch_bounds__(256) void k_Pt(const float* __restrict__ P, float* __restrict__ Pt) {
    int tid = blockIdx.x * 256 + threadIdx.x;   // 32768
    int b = tid >> 14;
    int d = (tid >> 7) & 127;
    int e = tid & 127;
    Pt[((size_t)b * 128 + e) * 128 + d] = P[tid];
}

// ---------------------------------------------------------------- k_scores2
// 64(i) x 128(j) tile; dual GEMM s0,s1 (K=128) + softmax/mhat/loss epilogue.
// Thread tile 4x8 per GEMM. LDS ~17 KB. codeR pre-reordered (coalesced).
__global__ __launch_bounds__(256) void k_scores2(const float* __restrict__ t01,  // [2][4096][128]
                                                 const float* __restrict__ vh,   // [4096][128]
                                                 const uint8_t* __restrict__ codeR,
                                                 const float* __restrict__ a_f,  // [2][5]
                                                 float* __restrict__ mhat,
                                                 float* __restrict__ accum) {
    __shared__ float T0s[16][68], T1s[16][68], Vs[16][132];
    __shared__ float sa[16];
    int t = threadIdx.x;
    int tx = t % 16, ty = t / 16;
    int j0 = blockIdx.x * 128, i0 = blockIdx.y * 64;
    if (t < 10) sa[t] = a_f[t];

    float s0a[4][8] = {}, s1a[4][8] = {};
    const float* T0g = t01;
    const float* T1g = t01 + (size_t)N4 * H1;
    // staging indices: A-side: row ai = t>>2, chunk ac = t&3 (4 f4 per row of 16 k)
    int ai = t >> 2, ac = t & 3;
    for (int k0 = 0; k0 < H1; k0 += 16) {
        float4 x0 = *(const float4*)(T0g + (size_t)(i0 + ai) * H1 + k0 + ac * 4);
        float4 x1 = *(const float4*)(T1g + (size_t)(i0 + ai) * H1 + k0 + ac * 4);
        T0s[ac * 4 + 0][ai] = x0.x; T0s[ac * 4 + 1][ai] = x0.y;
        T0s[ac * 4 + 2][ai] = x0.z; T0s[ac * 4 + 3][ai] = x0.w;
        T1s[ac * 4 + 0][ai] = x1.x; T1s[ac * 4 + 1][ai] = x1.y;
        T1s[ac * 4 + 2][ai] = x1.z; T1s[ac * 4 + 3][ai] = x1.w;
        #pragma unroll
        for (int l = 0; l < 2; l++) {
            int g = t + l * 256;
            int vj = g >> 2, vc = g & 3;
            float4 xv = *(const float4*)(vh + (size_t)(j0 + vj) * H1 + k0 + vc * 4);
            Vs[vc * 4 + 0][vj] = xv.x; Vs[vc * 4 + 1][vj] = xv.y;
            Vs[vc * 4 + 2][vj] = xv.z; Vs[vc * 4 + 3][vj] = xv.w;
        }
        __syncthreads();
        #pragma unroll
        for (int k = 0; k < 16; k++) {
            float a0[4], a1[4], bb[8];
            #pragma unroll
            for (int m = 0; m < 4; m++) { a0[m] = T0s[k][ty * 4 + m]; a1[m] = T1s[k][ty * 4 + m]; }
            #pragma unroll
            for (int n = 0; n < 8; n++) bb[n] = Vs[k][tx * 8 + n];
            #pragma unroll
            for (int m = 0; m < 4; m++)
                #pragma unroll
                for (int n = 0; n < 8; n++) {
                    s0a[m][n] = fmaf(a0[m], bb[n], s0a[m][n]);
                    s1a[m][n] = fmaf(a1[m], bb[n], s1a[m][n]);
                }
        }
        __syncthreads();
    }

    float lsum = 0.f, ssum = 0.f, nobs = 0.f;
    #pragma unroll
    for (int ii = 0; ii < 4; ii++) {
        int ig = i0 + ty * 4 + ii;
        // coalesced 8-byte code read for this thread's 8 columns
        uint8_t cb8[8];
        __builtin_memcpy(cb8, codeR + (size_t)ig * N4 + j0 + tx * 8, 8);
        float orow[8];
        #pragma unroll
        for (int jj = 0; jj < 8; jj++) {
            float v0 = s0a[ii][jj], v1 = s1a[ii][jj];
            float l[NC];
            float mx = -1e30f;
            #pragma unroll
            for (int c = 0; c < NC; c++) {
                l[c] = sa[c] * v0 + sa[5 + c] * v1;
                mx = fmaxf(mx, l[c]);
            }
            float den = 0.f, num = 0.f;
            #pragma unroll
            for (int c = 0; c < NC; c++) {
                float e = __expf(l[c] - mx);
                den += e;
                num += (float)(c + 1) * e;
            }
            float mh = num / den;
            orow[jj] = mh;
            int cb = cb8[jj];
            if (cb) {
                float lse = mx + __logf(den);
                lsum += lse - l[cb - 1];        // = -logp[cb-1]
                float df = mh - (float)cb;
                ssum += df * df;
                nobs += 1.f;
            }
        }
        float* mp = mhat + (size_t)ig * N4 + j0 + tx * 8;
        *(float4*)(mp + 0) = make_float4(orow[0], orow[1], orow[2], orow[3]);
        *(float4*)(mp + 4) = make_float4(orow[4], orow[5], orow[6], orow[7]);
    }
    #pragma unroll
    for (int off = 32; off; off >>= 1) {
        lsum += __shfl_down(lsum, off, 64);
        ssum += __shfl_down(ssum, off, 64);
        nobs += __shfl_down(nobs, off, 64);
    }
    if ((t & 63) == 0) {
        atomicAdd(accum + 0, lsum);
        atomicAdd(accum + 1, ssum);
        atomicAdd(accum + 2, nobs);
    }
}

// ---------------------------------------------------------------- k_finalize
__global__ void k_finalize(const float* __restrict__ accum, float* __restrict__ out) {
    float n = fmaxf(accum[2], 1.f);
    out[NUV + 0] = accum[0] / n;
    out[NUV + 1] = sqrtf(accum[1] / n);
}

// ================================================================ launch
extern "C" void kernel_launch(void* const* d_in, const int* in_sizes, int n_in,
                              void* d_out, int out_size, void* d_ws, size_t ws_size,
                              hipStream_t stream) {
    const int* u = (const int*)d_in[0];
    const int* v = (const int*)d_in[1];
    const float* adj    = (const float*)d_in[3];
    const float* u_feat = (const float*)d_in[4];
    const float* v_feat = (const float*)d_in[5];
    const float* u_w    = (const float*)d_in[6];
    const float* v_w    = (const float*)d_in[7];
    const float* Wu1    = (const float*)d_in[8];
    const float* bu1    = (const float*)d_in[9];
    const float* Wv1    = (const float*)d_in[10];
    const float* bv1    = (const float*)d_in[11];
    const float* Wu2    = (const float*)d_in[12];
    const float* Wv2    = (const float*)d_in[13];
    const float* P      = (const float*)d_in[14];
    const float* a      = (const float*)d_in[15];
    float* out = (float*)d_out;

    char* ws = (char*)d_ws;
    // workspace layout (bytes); total ~105 MB.
    // Overlays: codeT on UCAT (dead after k_compact);
    //           codeR on TAU+TBV f16 tables (dead after k_gather2).
    const size_t O_CODE  = 0;                         // 16,777,216 u8
    const size_t O_CNTU  = 16777216;                  // 16,384 i32
    const size_t O_CNTV  = O_CNTU + 16384;            // 16,384 i32
    const size_t O_ACC   = O_CNTV + 16384;            // 256 B
    const size_t O_TAU   = O_ACC + 256;               // 10,485,760 f16 table (u side)
    const size_t O_TBV   = O_TAU + 10485760;          // 10,485,760 f16 table (v side)
    const size_t O_IDXU  = O_TBV + 10485760;          // 12,582,912 u16 [4096][CAP]
    const size_t O_IDXV  = O_IDXU + 12582912;         // 12,582,912 u16
    const size_t O_NNZU  = O_IDXV + 12582912;         // 16,384 i32
    const size_t O_NNZV  = O_NNZU + 16384;            // 16,384 i32
    const size_t O_RDEG  = O_NNZV + 16384;            // 16,384 f32
    const size_t O_CDEG  = O_RDEG + 16384;            // 16,384 f32
    const size_t O_UNN   = O_CDEG + 16384;            // 4,194,304 f32
    const size_t O_VNN   = O_UNN + 4194304;           // 4,194,304 f32
    const size_t O_UCAT  = O_VNN + 4194304;           // 12,582,912 f32 [4096][768]
    const size_t O_VCAT  = O_UCAT + 12582912;         // 12,582,912 f32
    const size_t O_UH    = O_VCAT + 12582912;         // 2,097,152 f32
    const size_t O_VH    = O_UH + 2097152;            // 2,097,152 f32
    const size_t O_PT    = O_VH + 2097152;            // 131,072 f32
    const size_t O_T     = O_PT + 131072;             // 4,194,304 f32 [2][4096][128]
    const size_t O_CODET = O_UCAT;                    // overlay: 16,777,216 u8
    const size_t O_CODER = O_TAU;                     // overlay: 16,777,216 u8 (fits in TAU+TBV)

    uint8_t* code  = (uint8_t*)(ws + O_CODE);
    uint8_t* codeT = (uint8_t*)(ws + O_CODET);
    uint8_t* codeR = (uint8_t*)(ws + O_CODER);
    int* cnt_u = (int*)(ws + O_CNTU);
    int* cnt_v = (int*)(ws + O_CNTV);
    float* accum = (float*)(ws + O_ACC);
    unsigned short* T_Au = (unsigned short*)(ws + O_TAU);
    unsigned short* T_Bv = (unsigned short*)(ws + O_TBV);
    unsigned short* idxU = (unsigned short*)(ws + O_IDXU);
    unsigned short* idxV = (unsigned short*)(ws + O_IDXV);
    int* nnzU = (int*)(ws + O_NNZU);
    int* nnzV = (int*)(ws + O_NNZV);
    float* rowDeg = (float*)(ws + O_RDEG);
    float* colDeg = (float*)(ws + O_CDEG);
    float* u_nn = (float*)(ws + O_UNN);
    float* v_nn = (float*)(ws + O_VNN);
    float* ucat = (float*)(ws + O_UCAT);
    float* vcat = (float*)(ws + O_VCAT);
    float* uh = (float*)(ws + O_UH);
    float* vh = (float*)(ws + O_VH);
    float* Pt = (float*)(ws + O_PT);
    float* tbuf = (float*)(ws + O_T);

    hipMemsetAsync(ws + O_CNTU, 0, 16384 + 16384 + 256, stream);

    k_counts<<<16, 256, 0, stream>>>(u, v, cnt_u, cnt_v);
    k_code<<<16384, 256, 0, stream>>>(adj, (uchar4*)code);
    k_transpose<<<dim3(64, 64), 256, 0, stream>>>(code, codeT);
    k_wcumsum<<<N4, 256, 0, stream>>>(u_w, cnt_u, T_Au);
    k_wcumsum<<<N4, 256, 0, stream>>>(v_w, cnt_v, T_Bv);
    // u-direction: compact code rows; deg = rowDeg (weights cnt_v)
    k_compact<<<N4, 256, 0, stream>>>(code, cnt_v, idxU, nnzU, rowDeg);
    // v-direction: compact codeT rows; deg = colDeg (weights cnt_u)
    k_compact<<<N4, 256, 0, stream>>>(codeT, cnt_u, idxV, nnzV, colDeg);
    k_gather2<<<N4, 256, 0, stream>>>(idxU, nnzU, T_Bv, u_nn);
    k_gather2<<<N4, 256, 0, stream>>>(idxV, nnzV, T_Au, v_nn);
    // tables now dead -> build codeR over them
    k_reorder<<<N4, 256, 0, stream>>>(code, u, v, codeR);
    // u_z into ucat[:, :256]; v_z into vcat[:, :256]
    k_z<<<N4, 256, 0, stream>>>(u_nn, u, v, colDeg, ucat);
    k_z<<<N4, 256, 0, stream>>>(v_nn, v, u, rowDeg, vcat);
    // u_f = relu(u_features[u] @ Wu1^T + bu1) -> ucat[:, 256:768]
    k_gemm<128, 64, 16, 8, 4, true, true, true>
        <<<dim3(32, 8, 1), 256, 0, stream>>>(u_feat, SIDE, u, Wu1, SIDE, bu1,
                                             ucat + H0, HCAT, SIDE, 0, 0);
    k_gemm<128, 64, 16, 8, 4, true, true, true>
        <<<dim3(32, 8, 1), 256, 0, stream>>>(v_feat, SIDE, v, Wv1, SIDE, bv1,
                                             vcat + H0, HCAT, SIDE, 0, 0);
    // u_h = relu(ucat @ Wu2^T)
    k_gemm<64, 32, 16, 4, 2, false, false, true>
        <<<dim3(64, 4, 1), 256, 0, stream>>>(ucat, HCAT, nullptr, Wu2, HCAT, nullptr,
                                             uh, H1, HCAT, 0, 0);
    k_gemm<64, 32, 16, 4, 2, false, false, true>
        <<<dim3(64, 4, 1), 256, 0, stream>>>(vcat, HCAT, nullptr, Wv2, HCAT, nullptr,
                                             vh, H1, HCAT, 0, 0);
    k_Pt<<<128, 256, 0, stream>>>(P, Pt);
    // t[b] = uh @ P[b]  (as NT with Pt[b][e][d])
    k_gemm<64, 32, 16, 4, 2, false, false, false>
        <<<dim3(64, 4, 2), 256, 0, stream>>>(uh, H1, nullptr, Pt, H1, nullptr,
                                             tbuf, H1, H1, (size_t)H1 * H1, (size_t)N4 * H1);
    k_scores2<<<dim3(32, 64), 256, 0, stream>>>(tbuf, vh, codeR, a, out, accum);
    k_finalize<<<1, 1, 0, stream>>>(accum, out);
}

// Round 5
// 1896.456 us; speedup vs baseline: 1.7611x; 1.0049x over previous
//
#include <hip/hip_runtime.h>
#include <stdint.h>

// Problem constants
#define N4   4096
#define H0   256
#define SIDE 1024
#define DIN  512
#define HCAT 768      // H0 + DIN
#define H1   128
#define NC   5
#define NUV  16777216ULL   // 4096*4096
#define CAP  1536          // max compacted entries per row

typedef __attribute__((ext_vector_type(8))) short short8;    // 8 bf16
typedef __attribute__((ext_vector_type(4))) float floatx4;

__device__ __forceinline__ unsigned short f2bf(float f) {
    unsigned int u;
    __builtin_memcpy(&u, &f, 4);
    unsigned int r = (u + 0x7FFFu + ((u >> 16) & 1u)) >> 16;   // RNE
    return (unsigned short)r;
}

// ---------------------------------------------------------------- k_counts
__global__ __launch_bounds__(256) void k_counts(const int* __restrict__ u,
                                                const int* __restrict__ v,
                                                int* __restrict__ cu,
                                                int* __restrict__ cv) {
    int i = blockIdx.x * 256 + threadIdx.x;   // 4096 threads
    atomicAdd(&cu[u[i]], 1);
    atomicAdd(&cv[v[i]], 1);
}

// ---------------------------------------------------------------- k_code
__global__ __launch_bounds__(256) void k_code(const float* __restrict__ adj,
                                              uchar4* __restrict__ code4) {
    size_t g = (size_t)blockIdx.x * 256 + threadIdx.x;
    size_t base = g * 4;
    uchar4 out = {0, 0, 0, 0};
    #pragma unroll
    for (int c = 0; c < NC; c++) {
        float4 s = *(const float4*)(adj + (size_t)c * NUV + base);
        out.x = (s.x != 0.f) ? (unsigned char)(c + 1) : out.x;
        out.y = (s.y != 0.f) ? (unsigned char)(c + 1) : out.y;
        out.z = (s.z != 0.f) ? (unsigned char)(c + 1) : out.z;
        out.w = (s.w != 0.f) ? (unsigned char)(c + 1) : out.w;
    }
    code4[g] = out;
}

// ---------------------------------------------------------------- k_transpose (byte, 64x64 tiles)
__global__ __launch_bounds__(256) void k_transpose(const uint8_t* __restrict__ src,
                                                   uint8_t* __restrict__ dst) {
    __shared__ __align__(16) uint8_t tile[64][80];
    int t = threadIdx.x;
    int row = t >> 2;
    int seg = (t & 3) * 16;
    int p0 = blockIdx.y * 64, q0 = blockIdx.x * 64;
    uint4 vdat = *(const uint4*)(src + (size_t)(p0 + row) * N4 + q0 + seg);
    *(uint4*)(&tile[row][seg]) = vdat;
    __syncthreads();
    union { uint4 u4; uint8_t b[16]; } o;
    #pragma unroll
    for (int l = 0; l < 16; l++) o.b[l] = tile[seg + l][row];
    *(uint4*)(dst + (size_t)(q0 + row) * N4 + p0 + seg) = o.u4;
}

// ---------------------------------------------------------------- k_wcumsum
// out[r][node][h] = f16( cnt[node] * cumsum_r(w)[r][node][h] )
__global__ __launch_bounds__(256) void k_wcumsum(const float* __restrict__ w,
                                                 const int* __restrict__ cnt,
                                                 unsigned short* __restrict__ out) {
    int node = blockIdx.x, h = threadIdx.x;
    float c = (float)cnt[node];
    float acc = 0.f;
    #pragma unroll
    for (int r = 0; r < NC; r++) {
        size_t idx = ((size_t)r * N4 + node) * H0 + h;
        acc += w[idx];
        union { _Float16 h16; unsigned short s; } cvt;
        cvt.h16 = (_Float16)(acc * c);
        out[idx] = cvt.s;
    }
}

// ---------------------------------------------------------------- k_compact
// Compact one code row into entry list (ushort: (r-1)*4096+q), plus
// deg[p] and nnz[p]. Shfl-based scan: 2 barriers total.
__global__ __launch_bounds__(256) void k_compact(const uint8_t* __restrict__ codeRows,
                                                 const int* __restrict__ cntOther,
                                                 unsigned short* __restrict__ idx,
                                                 int* __restrict__ nnz,
                                                 float* __restrict__ deg) {
    __shared__ float cw[4096];
    __shared__ int wtot[4];
    __shared__ float wdeg[4];
    __shared__ unsigned short ebuf[CAP];
    int p = blockIdx.x, t = threadIdx.x;
    int lane = t & 63, wv = t >> 6;
    const int4* co4 = (const int4*)cntOther;
    #pragma unroll
    for (int l = 0; l < 4; l++) {
        int4 ci = co4[t + l * 256];
        ((float4*)cw)[t + l * 256] =
            make_float4((float)ci.x, (float)ci.y, (float)ci.z, (float)ci.w);
    }
    uint4 w = ((const uint4*)(codeRows + (size_t)p * N4))[t];
    unsigned char b[16];
    __builtin_memcpy(b, &w, 16);
    int cnt = 0;
    #pragma unroll
    for (int j = 0; j < 16; j++) cnt += (b[j] != 0);
    // wave-level inclusive scan (no barriers)
    int sc = cnt;
    #pragma unroll
    for (int off = 1; off < 64; off <<= 1) {
        int up = __shfl_up(sc, off, 64);
        if (lane >= off) sc += up;
    }
    if (lane == 63) wtot[wv] = sc;
    __syncthreads();            // covers cw + wtot
    int wbase = 0;
    #pragma unroll
    for (int ww = 0; ww < 4; ww++) wbase += (ww < wv) ? wtot[ww] : 0;
    int total = wtot[0] + wtot[1] + wtot[2] + wtot[3];
    int pos = wbase + sc - cnt;   // block-exclusive prefix
    float dsum = 0.f;
    #pragma unroll
    for (int j = 0; j < 16; j++) {
        int r = b[j];
        if (r) {
            int q = t * 16 + j;
            if (pos < CAP) ebuf[pos] = (unsigned short)((r - 1) * N4 + q);
            pos++;
            dsum += cw[q];
        }
    }
    #pragma unroll
    for (int off = 32; off; off >>= 1) dsum += __shfl_down(dsum, off, 64);
    if (lane == 0) wdeg[wv] = dsum;
    __syncthreads();            // covers ebuf + wdeg
    int tw = total < CAP ? total : CAP;
    if (t == 0) { deg[p] = wdeg[0] + wdeg[1] + wdeg[2] + wdeg[3]; nnz[p] = tw; }
    for (int e = t; e < tw; e += 256) idx[(size_t)p * CAP + e] = ebuf[e];
}

// ---------------------------------------------------------------- k_gather2
__global__ __launch_bounds__(256) void k_gather2(const unsigned short* __restrict__ idx,
                                                 const int* __restrict__ nnz,
                                                 const unsigned short* __restrict__ tbl,
                                                 float* __restrict__ outNN) {
    __shared__ unsigned short sidx[256];
    __shared__ float red[512];
    int p = blockIdx.x, t = threadIdx.x;
    int n = nnz[p];
    int half = t >> 7, hp = t & 127;
    const char* tb = (const char*)tbl;
    const unsigned short* rowIdx = idx + (size_t)p * CAP;
    float a0 = 0.f, a1 = 0.f;
    for (int base = 0; base < n; base += 256) {
        int m = n - base; if (m > 256) m = 256;
        if (t < m) sidx[t] = rowIdx[base + t];
        __syncthreads();
        for (int e = half; e < m; e += 2) {
            int off = ((int)sidx[e]) << 9;          // *512 bytes per table row
            unsigned d = *(const unsigned*)(tb + off + hp * 4);
            union { unsigned u; _Float16 h[2]; } cv; cv.u = d;
            a0 += (float)cv.h[0];
            a1 += (float)cv.h[1];
        }
        __syncthreads();
    }
    red[t] = a0; red[256 + t] = a1;
    __syncthreads();
    if (t < 128) {
        float r0 = red[t] + red[128 + t];
        float r1 = red[256 + t] + red[384 + t];
        *(float2*)(outNN + (size_t)p * H0 + 2 * hp) = make_float2(r0, r1);
    }
}

// ---------------------------------------------------------------- k_reorder
// codeR[i][j] = code[u[i]][v[j]]
__global__ __launch_bounds__(256) void k_reorder(const uint8_t* __restrict__ code,
                                                 const int* __restrict__ u,
                                                 const int* __restrict__ v,
                                                 uint8_t* __restrict__ codeR) {
    __shared__ __align__(16) uint8_t rowbuf[4096];
    int i = blockIdx.x, t = threadIdx.x;
    int urow = u[i];
    ((uint4*)rowbuf)[t] = ((const uint4*)(code + (size_t)urow * N4))[t];
    __syncthreads();
    uint8_t ob[16];
    #pragma unroll
    for (int w = 0; w < 4; w++) {
        int4 vv = ((const int4*)v)[t * 4 + w];
        ob[w * 4 + 0] = rowbuf[vv.x];
        ob[w * 4 + 1] = rowbuf[vv.y];
        ob[w * 4 + 2] = rowbuf[vv.z];
        ob[w * 4 + 3] = rowbuf[vv.w];
    }
    uint4 o;
    __builtin_memcpy(&o, ob, 16);
    ((uint4*)(codeR + (size_t)i * N4))[t] = o;
}

// ---------------------------------------------------------------- k_z
__global__ __launch_bounds__(256) void k_z(const float* __restrict__ nn,
                                           const int* __restrict__ idxs,
                                           const int* __restrict__ idxo,
                                           const float* __restrict__ deg,
                                           float* __restrict__ cat) {
    int i = blockIdx.x, h = threadIdx.x;
    float d = deg[idxo[i]];
    float inv = d > 0.f ? 1.f / d : 0.f;
    float val = nn[(size_t)idxs[i] * H0 + h] * inv;
    cat[(size_t)i * HCAT + h] = fmaxf(val, 0.f);
}

// ---------------------------------------------------------------- generic NT GEMM (fp32 in, fp32 or bf16 out)
template <int TM, int TN, int BK, int RM, int RN, bool GATHER, bool BIAS, bool RELU, bool BF16OUT>
__global__ __launch_bounds__(256) void k_gemm(const float* __restrict__ A, int lda,
                                              const int* __restrict__ rowmap,
                                              const float* __restrict__ B, int ldb,
                                              const float* __restrict__ bias,
                                              float* __restrict__ C, int ldc, int K,
                                              size_t bzs, size_t czs) {
    constexpr int TX = TN / RN;
    constexpr int TY = TM / RM;
    static_assert(TX * TY == 256, "block must be 256");
    __shared__ float As[BK][TM + 4];
    __shared__ float Bs[BK][TN + 4];
    int tid = threadIdx.x;
    int tx = tid % TX, ty = tid / TX;
    int i0 = blockIdx.x * TM, n0 = blockIdx.y * TN;
    const float* Bz = B + (size_t)blockIdx.z * bzs;
    float acc[RM][RN] = {};
    for (int k0 = 0; k0 < K; k0 += BK) {
        for (int g = tid; g < TM * BK / 4; g += 256) {
            int i = g / (BK / 4), kc = g % (BK / 4);
            int row = GATHER ? rowmap[i0 + i] : (i0 + i);
            float4 val = *(const float4*)(A + (size_t)row * lda + k0 + kc * 4);
            As[kc * 4 + 0][i] = val.x; As[kc * 4 + 1][i] = val.y;
            As[kc * 4 + 2][i] = val.z; As[kc * 4 + 3][i] = val.w;
        }
        for (int g = tid; g < TN * BK / 4; g += 256) {
            int n = g / (BK / 4), kc = g % (BK / 4);
            float4 val = *(const float4*)(Bz + (size_t)(n0 + n) * ldb + k0 + kc * 4);
            Bs[kc * 4 + 0][n] = val.x; Bs[kc * 4 + 1][n] = val.y;
            Bs[kc * 4 + 2][n] = val.z; Bs[kc * 4 + 3][n] = val.w;
        }
        __syncthreads();
        #pragma unroll
        for (int k = 0; k < BK; k++) {
            float av[RM], bv[RN];
            #pragma unroll
            for (int m = 0; m < RM; m++) av[m] = As[k][ty * RM + m];
            #pragma unroll
            for (int n = 0; n < RN; n++) bv[n] = Bs[k][tx * RN + n];
            #pragma unroll
            for (int m = 0; m < RM; m++)
                #pragma unroll
                for (int n = 0; n < RN; n++)
                    acc[m][n] = fmaf(av[m], bv[n], acc[m][n]);
        }
        __syncthreads();
    }
    #pragma unroll
    for (int m = 0; m < RM; m++) {
        int ig = i0 + ty * RM + m;
        #pragma unroll
        for (int n = 0; n < RN; n++) {
            float vv = acc[m][n];
            if (BIAS) vv += bias[n0 + tx * RN + n];
            if (RELU) vv = fmaxf(vv, 0.f);
            if (BF16OUT) {
                unsigned short* Cz16 = (unsigned short*)C + (size_t)blockIdx.z * czs;
                Cz16[(size_t)ig * ldc + n0 + tx * RN + n] = f2bf(vv);
            } else {
                float* Cz = C + (size_t)blockIdx.z * czs;
                Cz[(size_t)ig * ldc + n0 + tx * RN + n] = vv;
            }
        }
    }
}

// ---------------------------------------------------------------- k_Pt : Pt[b][e][d] = P[b][d][e]
__global__ __launch_bounds__(256) void k_Pt(const float* __restrict__ P, float* __restrict__ Pt) {
    int tid = blockIdx.x * 256 + threadIdx.x;   // 32768
    int b = tid >> 14;
    int d = (tid >> 7) & 127;
    int e = tid & 127;
    Pt[((size_t)b * 128 + e) * 128 + d] = P[tid];
}

// ---------------------------------------------------------------- k_scores3 (MFMA bf16 decoder + softmax epilogue)
// Tile: 64 i x 128 j per block (4 waves, one 16-row strip each). No LDS.
// A frag: tb[b][i0+lr][kc*32+lk*8 ..+8]; B frag: vhb[jb+lr][kc*32+lk*8 ..+8]
// C/D: col=lane&15, row=(lane>>4)*4+reg (m89-verified layout).
__global__ __launch_bounds__(256) void k_scores3(const unsigned short* __restrict__ tb,  // [2][4096][128] bf16
                                                 const unsigned short* __restrict__ vhb, // [4096][128] bf16
                                                 const uint8_t* __restrict__ codeR,
                                                 const float* __restrict__ a_f,          // [2][5]
                                                 float* __restrict__ mhat,
                                                 float* __restrict__ accum) {
    int t = threadIdx.x;
    int wave = t >> 6, lane = t & 63;
    int lr = lane & 15;          // A row / B col / C col
    int lk = lane >> 4;          // k-subgroup & C row-group
    int i0 = blockIdx.y * 64 + wave * 16;
    int j0 = blockIdx.x * 128;
    float sa0[NC], sa1[NC];
    #pragma unroll
    for (int c = 0; c < NC; c++) { sa0[c] = a_f[c]; sa1[c] = a_f[5 + c]; }

    const unsigned short* t0p = tb;
    const unsigned short* t1p = tb + (size_t)N4 * H1;
    short8 a0[4], a1[4];
    #pragma unroll
    for (int kc = 0; kc < 4; kc++) {
        size_t off = (size_t)(i0 + lr) * H1 + kc * 32 + lk * 8;
        a0[kc] = *(const short8*)(t0p + off);
        a1[kc] = *(const short8*)(t1p + off);
    }

    float lsum = 0.f, ssum = 0.f, nobs = 0.f;
    for (int jt = 0; jt < 8; jt++) {
        int jb = j0 + jt * 16;
        floatx4 C0 = {0.f, 0.f, 0.f, 0.f}, C1 = {0.f, 0.f, 0.f, 0.f};
        #pragma unroll
        for (int kc = 0; kc < 4; kc++) {
            short8 b = *(const short8*)(vhb + (size_t)(jb + lr) * H1 + kc * 32 + lk * 8);
            C0 = __builtin_amdgcn_mfma_f32_16x16x32_bf16(a0[kc], b, C0, 0, 0, 0);
            C1 = __builtin_amdgcn_mfma_f32_16x16x32_bf16(a1[kc], b, C1, 0, 0, 0);
        }
        int j = jb + lr;
        #pragma unroll
        for (int r = 0; r < 4; r++) {
            int i = i0 + lk * 4 + r;
            float v0 = C0[r], v1 = C1[r];
            float l[NC];
            float mx = -1e30f;
            #pragma unroll
            for (int c = 0; c < NC; c++) {
                l[c] = sa0[c] * v0 + sa1[c] * v1;
                mx = fmaxf(mx, l[c]);
            }
            float den = 0.f, num = 0.f;
            #pragma unroll
            for (int c = 0; c < NC; c++) {
                float e = __expf(l[c] - mx);
                den += e;
                num += (float)(c + 1) * e;
            }
            float mh = num / den;
            mhat[(size_t)i * N4 + j] = mh;
            int cb = codeR[(size_t)i * N4 + j];
            if (cb) {
                float lse = mx + __logf(den);
                lsum += lse - l[cb - 1];        // = -logp[cb-1]
                float df = mh - (float)cb;
                ssum += df * df;
                nobs += 1.f;
            }
        }
    }
    #pragma unroll
    for (int off = 32; off; off >>= 1) {
        lsum += __shfl_down(lsum, off, 64);
        ssum += __shfl_down(ssum, off, 64);
        nobs += __shfl_down(nobs, off, 64);
    }
    if (lane == 0) {
        atomicAdd(accum + 0, lsum);
        atomicAdd(accum + 1, ssum);
        atomicAdd(accum + 2, nobs);
    }
}

// ---------------------------------------------------------------- k_finalize
__global__ void k_finalize(const float* __restrict__ accum, float* __restrict__ out) {
    float n = fmaxf(accum[2], 1.f);
    out[NUV + 0] = accum[0] / n;
    out[NUV + 1] = sqrtf(accum[1] / n);
}

// ================================================================ launch
extern "C" void kernel_launch(void* const* d_in, const int* in_sizes, int n_in,
                              void* d_out, int out_size, void* d_ws, size_t ws_size,
                              hipStream_t stream) {
    const int* u = (const int*)d_in[0];
    const int* v = (const int*)d_in[1];
    const float* adj    = (const float*)d_in[3];
    const float* u_feat = (const float*)d_in[4];
    const float* v_feat = (const float*)d_in[5];
    const float* u_w    = (const float*)d_in[6];
    const float* v_w    = (const float*)d_in[7];
    const float* Wu1    = (const float*)d_in[8];
    const float* bu1    = (const float*)d_in[9];
    const float* Wv1    = (const float*)d_in[10];
    const float* bv1    = (const float*)d_in[11];
    const float* Wu2    = (const float*)d_in[12];
    const float* Wv2    = (const float*)d_in[13];
    const float* P      = (const float*)d_in[14];
    const float* a      = (const float*)d_in[15];
    float* out = (float*)d_out;

    char* ws = (char*)d_ws;
    // workspace layout (bytes); total ~100 MB.
    // Overlays: codeT on UCAT (dead after k_compact);
    //           codeR on TAU+TBV f16 tables (dead after k_gather2).
    const size_t O_CODE  = 0;                         // 16,777,216 u8
    const size_t O_CNTU  = 16777216;                  // 16,384 i32
    const size_t O_CNTV  = O_CNTU + 16384;            // 16,384 i32
    const size_t O_ACC   = O_CNTV + 16384;            // 256 B
    const size_t O_TAU   = O_ACC + 256;               // 10,485,760 f16 table (u side)
    const size_t O_TBV   = O_TAU + 10485760;          // 10,485,760 f16 table (v side)
    const size_t O_IDXU  = O_TBV + 10485760;          // 12,582,912 u16 [4096][CAP]
    const size_t O_IDXV  = O_IDXU + 12582912;         // 12,582,912 u16
    const size_t O_NNZU  = O_IDXV + 12582912;         // 16,384 i32
    const size_t O_NNZV  = O_NNZU + 16384;            // 16,384 i32
    const size_t O_RDEG  = O_NNZV + 16384;            // 16,384 f32
    const size_t O_CDEG  = O_RDEG + 16384;            // 16,384 f32
    const size_t O_UNN   = O_CDEG + 16384;            // 4,194,304 f32
    const size_t O_VNN   = O_UNN + 4194304;           // 4,194,304 f32
    const size_t O_UCAT  = O_VNN + 4194304;           // 12,582,912 f32 [4096][768]
    const size_t O_VCAT  = O_UCAT + 12582912;         // 12,582,912 f32
    const size_t O_UH    = O_VCAT + 12582912;         // 2,097,152 f32
    const size_t O_VHB   = O_UH + 2097152;            // 1,048,576 bf16 [4096][128]
    const size_t O_PT    = O_VHB + 1048576;           // 131,072 f32
    const size_t O_TB    = O_PT + 131072;             // 2,097,152 bf16 [2][4096][128]
    const size_t O_CODET = O_UCAT;                    // overlay
    const size_t O_CODER = O_TAU;                     // overlay (fits TAU+TBV)

    uint8_t* code  = (uint8_t*)(ws + O_CODE);
    uint8_t* codeT = (uint8_t*)(ws + O_CODET);
    uint8_t* codeR = (uint8_t*)(ws + O_CODER);
    int* cnt_u = (int*)(ws + O_CNTU);
    int* cnt_v = (int*)(ws + O_CNTV);
    float* accum = (float*)(ws + O_ACC);
    unsigned short* T_Au = (unsigned short*)(ws + O_TAU);
    unsigned short* T_Bv = (unsigned short*)(ws + O_TBV);
    unsigned short* idxU = (unsigned short*)(ws + O_IDXU);
    unsigned short* idxV = (unsigned short*)(ws + O_IDXV);
    int* nnzU = (int*)(ws + O_NNZU);
    int* nnzV = (int*)(ws + O_NNZV);
    float* rowDeg = (float*)(ws + O_RDEG);
    float* colDeg = (float*)(ws + O_CDEG);
    float* u_nn = (float*)(ws + O_UNN);
    float* v_nn = (float*)(ws + O_VNN);
    float* ucat = (float*)(ws + O_UCAT);
    float* vcat = (float*)(ws + O_VCAT);
    float* uh = (float*)(ws + O_UH);
    unsigned short* vhb = (unsigned short*)(ws + O_VHB);
    float* Pt = (float*)(ws + O_PT);
    unsigned short* tb = (unsigned short*)(ws + O_TB);

    hipMemsetAsync(ws + O_CNTU, 0, 16384 + 16384 + 256, stream);

    k_counts<<<16, 256, 0, stream>>>(u, v, cnt_u, cnt_v);
    k_code<<<16384, 256, 0, stream>>>(adj, (uchar4*)code);
    k_transpose<<<dim3(64, 64), 256, 0, stream>>>(code, codeT);
    k_wcumsum<<<N4, 256, 0, stream>>>(u_w, cnt_u, T_Au);
    k_wcumsum<<<N4, 256, 0, stream>>>(v_w, cnt_v, T_Bv);
    k_compact<<<N4, 256, 0, stream>>>(code, cnt_v, idxU, nnzU, rowDeg);
    k_compact<<<N4, 256, 0, stream>>>(codeT, cnt_u, idxV, nnzV, colDeg);
    k_gather2<<<N4, 256, 0, stream>>>(idxU, nnzU, T_Bv, u_nn);
    k_gather2<<<N4, 256, 0, stream>>>(idxV, nnzV, T_Au, v_nn);
    // tables now dead -> build codeR over them
    k_reorder<<<N4, 256, 0, stream>>>(code, u, v, codeR);
    k_z<<<N4, 256, 0, stream>>>(u_nn, u, v, colDeg, ucat);
    k_z<<<N4, 256, 0, stream>>>(v_nn, v, u, rowDeg, vcat);
    // u_f = relu(u_features[u] @ Wu1^T + bu1) -> ucat[:, 256:768]
    k_gemm<128, 64, 16, 8, 4, true, true, true, false>
        <<<dim3(32, 8, 1), 256, 0, stream>>>(u_feat, SIDE, u, Wu1, SIDE, bu1,
                                             ucat + H0, HCAT, SIDE, 0, 0);
    k_gemm<128, 64, 16, 8, 4, true, true, true, false>
        <<<dim3(32, 8, 1), 256, 0, stream>>>(v_feat, SIDE, v, Wv1, SIDE, bv1,
                                             vcat + H0, HCAT, SIDE, 0, 0);
    // u_h = relu(ucat @ Wu2^T) -> fp32 (feeds tbuf GEMM)
    k_gemm<64, 32, 16, 4, 2, false, false, true, false>
        <<<dim3(64, 4, 1), 256, 0, stream>>>(ucat, HCAT, nullptr, Wu2, HCAT, nullptr,
                                             uh, H1, HCAT, 0, 0);
    // v_h = relu(vcat @ Wv2^T) -> bf16 directly
    k_gemm<64, 32, 16, 4, 2, false, false, true, true>
        <<<dim3(64, 4, 1), 256, 0, stream>>>(vcat, HCAT, nullptr, Wv2, HCAT, nullptr,
                                             (float*)vhb, H1, HCAT, 0, 0);
    k_Pt<<<128, 256, 0, stream>>>(P, Pt);
    // t[b] = uh @ P[b] -> bf16 directly
    k_gemm<64, 32, 16, 4, 2, false, false, false, true>
        <<<dim3(64, 4, 2), 256, 0, stream>>>(uh, H1, nullptr, Pt, H1, nullptr,
                                             (float*)tb, H1, H1,
                                             (size_t)H1 * H1, (size_t)N4 * H1);
    k_scores3<<<dim3(32, 64), 256, 0, stream>>>(tb, vhb, codeR, a, out, accum);
    k_finalize<<<1, 1, 0, stream>>>(accum, out);
}